// Round 4
// baseline (3643.945 us; speedup 1.0000x reference)
//
#include <hip/hip_runtime.h>
#include <hip/hip_bf16.h>

#define NB    8
#define NPTS  8192
#define P_OUT 2048
#define KNN   32
#define CIN   128
#define CMID  16
#define COUT  256

typedef __bf16 bf16x8 __attribute__((ext_vector_type(8)));
typedef float  f32x4  __attribute__((ext_vector_type(4)));

// Correctly-rounded f32 sqrt via double (53>=2p+2 bits: double-rounding safe).
__device__ __forceinline__ float sqrt_rn_f32(float x) { return (float)sqrt((double)x); }

// RNE float->bf16 (finite inputs only)
__device__ __forceinline__ unsigned short f2bf(float x) {
    unsigned u = __float_as_uint(x);
    return (unsigned short)((u + 0x7FFFu + ((u >> 16) & 1u)) >> 16);
}

// ---------------------------------------------------------------------------
// prep: (z, |p|^2) per point (|p|^2 = no-FMA rn chain, matches XLA reduce),
// and lin_w -> bf16
// ---------------------------------------------------------------------------
__global__ __launch_bounds__(256) void prep_kernel(const float* __restrict__ coords,
                                                   const float* __restrict__ lin_w,
                                                   float2* __restrict__ zp,
                                                   unsigned short* __restrict__ lwbf) {
    const int i = blockIdx.x * 256 + threadIdx.x;
    if (i < NB * NPTS) {
        const float* pc = coords + (size_t)i * 3;
        const float x = pc[0], y = pc[1], z = pc[2];
        float t = __fmul_rn(x, x);
        t = __fadd_rn(t, __fmul_rn(y, y));
        t = __fadd_rn(t, __fmul_rn(z, z));
        zp[i] = make_float2(z, t);
    }
    if (i < COUT * CIN * CMID) lwbf[i] = f2bf(lin_w[i]);
}

// ---------------------------------------------------------------------------
// FPS: one workgroup per batch. 1024 thr x 8 consecutive points in registers.
// f32 d^2 domain (no-FMA rn chain = XLA mul+reduce); argmax-over-sqrt ties
// reproduced via correctly-rounded-sqrt ulp window. PASSED round 1 verbatim.
// ---------------------------------------------------------------------------
__global__ __launch_bounds__(1024) void fps_kernel(const float* __restrict__ coords,
                                                   float* __restrict__ out_coords) {
    const int b    = blockIdx.x;
    const int tid  = threadIdx.x;
    const int lane = tid & 63;
    const int wv   = tid >> 6;
    const float* cb = coords + (size_t)b * (NPTS * 3);
    float* outc = out_coords + (size_t)b * (P_OUT * 3);

    __shared__ __align__(16) float warr[16];
    __shared__ unsigned winslot;
    __shared__ float csl[3];

    float px[8], py[8], pz[8], d2a[8];
    {
        float buf[24];
        const float4* g4 = (const float4*)cb;
        #pragma unroll
        for (int i = 0; i < 6; ++i) {
            float4 v = g4[tid * 6 + i];
            buf[i*4+0] = v.x; buf[i*4+1] = v.y; buf[i*4+2] = v.z; buf[i*4+3] = v.w;
        }
        #pragma unroll
        for (int i = 0; i < 8; ++i) {
            px[i] = buf[i*3+0]; py[i] = buf[i*3+1]; pz[i] = buf[i*3+2];
            d2a[i] = __builtin_inff();
        }
    }
    if (tid == 0) {
        csl[0] = px[0]; csl[1] = py[0]; csl[2] = pz[0];  // point 0 is the seed
        winslot = 0xFFFFFFFFu;
    }
    __syncthreads();
    float cx = csl[0], cy = csl[1], cz = csl[2];

    for (int s = 0; s < P_OUT; ++s) {
        if (tid == 0) { outc[s*3+0] = cx; outc[s*3+1] = cy; outc[s*3+2] = cz; }
        if (s == P_OUT - 1) break;

        // min-update in d^2 (exact: sub/mul/add rn, no fma), track thread max
        float tmax = 0.0f;
        #pragma unroll
        for (int i = 0; i < 8; ++i) {
            float dx = __fsub_rn(px[i], cx);
            float dy = __fsub_rn(py[i], cy);
            float dz = __fsub_rn(pz[i], cz);
            float t  = __fmul_rn(dx, dx);
            t = __fadd_rn(t, __fmul_rn(dy, dy));
            t = __fadd_rn(t, __fmul_rn(dz, dz));
            float nd = fminf(d2a[i], t);
            d2a[i] = nd;
            tmax = fmaxf(tmax, nd);
        }
        // wave max (value only)
        float wmax = tmax;
        #pragma unroll
        for (int off = 32; off > 0; off >>= 1)
            wmax = fmaxf(wmax, __shfl_xor(wmax, off, 64));
        if (lane == 0) warr[wv] = wmax;
        __syncthreads();  // BAR A

        float4 q0 = *(const float4*)(warr + 0);
        float4 q1 = *(const float4*)(warr + 4);
        float4 q2 = *(const float4*)(warr + 8);
        float4 q3 = *(const float4*)(warr + 12);
        float gmax = fmaxf(
            fmaxf(fmaxf(fmaxf(q0.x,q0.y), fmaxf(q0.z,q0.w)),
                  fmaxf(fmaxf(q1.x,q1.y), fmaxf(q1.z,q1.w))),
            fmaxf(fmaxf(fmaxf(q2.x,q2.y), fmaxf(q2.z,q2.w)),
                  fmaxf(fmaxf(q3.x,q3.y), fmaxf(q3.z,q3.w))));

        // only waves within 3 ulps of gmax can hold the winner (window <= 4 ulps)
        if (__float_as_uint(wmax) + 3u >= __float_as_uint(gmax)) {
            const float s_ = sqrt_rn_f32(gmax);
            float t_lo = gmax;
            const unsigned gb = __float_as_uint(gmax);
            #pragma unroll
            for (int j = 1; j <= 3; ++j) {
                float v = __uint_as_float(gb - j);
                if (sqrt_rn_f32(v) == s_) t_lo = v;   // monotone: extends window downward
            }
            unsigned cand = 0xFFFFFFFFu;
            #pragma unroll
            for (int i = 7; i >= 0; --i)
                if (d2a[i] >= t_lo) cand = (unsigned)(tid * 8 + i);  // smallest local idx
            if (cand != 0xFFFFFFFFu) atomicMin(&winslot, cand);      // smallest global idx
        }
        __syncthreads();  // BAR B

        const unsigned widx = winslot;
        #pragma unroll
        for (int i = 0; i < 8; ++i) {
            if (widx == (unsigned)(tid * 8 + i)) {  // owner publishes centroid
                csl[0] = px[i]; csl[1] = py[i]; csl[2] = pz[i];
            }
        }
        __syncthreads();  // BAR C
        if (tid == 0) winslot = 0xFFFFFFFFu;        // safe: next atomics after next BAR A
        cx = csl[0]; cy = csl[1]; cz = csl[2];
    }
}

// ---------------------------------------------------------------------------
// KNN: wave-per-center, distributed sorted top-32 list in lanes (lex (d2,idx)
// order == lax.top_k stability). d2 = f32 gram trick with the contraction's
// FMA chain (XLA dot_general / Eigen gebp): dot = fma(cz,z, fma(cy,y, cx*x));
// cc/pp stay no-FMA rn chains (separate mul+reduce HLOs). xy staged in 64KB
// LDS; (z,|p|^2) streamed from L2-resident buffer. XCD affinity: blk%8.
// ---------------------------------------------------------------------------
__global__ __launch_bounds__(1024) void knn_kernel(const float* __restrict__ coords,
                                                   const float2* __restrict__ zp,
                                                   const float* __restrict__ out_coords,
                                                   int* __restrict__ nbr) {
    const int b     = blockIdx.x & 7;
    const int chunk = blockIdx.x >> 3;
    const int tid   = threadIdx.x;
    const int wv    = tid >> 6, lane = tid & 63;
    __shared__ float2 sxy[NPTS];  // 64 KB exactly
    {
        float buf[24];
        const float4* g4 = (const float4*)(coords + (size_t)b * (NPTS * 3));
        #pragma unroll
        for (int i = 0; i < 6; ++i) {
            float4 v = g4[tid * 6 + i];
            buf[i*4+0]=v.x; buf[i*4+1]=v.y; buf[i*4+2]=v.z; buf[i*4+3]=v.w;
        }
        #pragma unroll
        for (int i = 0; i < 8; ++i)
            sxy[tid*8 + i] = make_float2(buf[i*3+0], buf[i*3+1]);
    }
    __syncthreads();
    const float2* zpb = zp + (size_t)b * NPTS;

    for (int ci = 0; ci < 4; ++ci) {
        const int p = chunk * 64 + wv * 4 + ci;
        const float* oc = out_coords + ((size_t)b * P_OUT + p) * 3;
        const float cx = oc[0], cy = oc[1], cz = oc[2];
        const float cc = __fadd_rn(__fadd_rn(__fmul_rn(cx,cx), __fmul_rn(cy,cy)), __fmul_rn(cz,cz));
        float ld2 = __builtin_inff();
        unsigned lidx = 0x7FFFFFFFu;
        for (int j0 = 0; j0 < NPTS; j0 += 64) {
            const int p2 = j0 + lane;
            const float2 xy = sxy[p2];
            const float2 zq = zpb[p2];
            // oracle contraction: FMA chain over d=0,1,2 (first product plain rn)
            const float dot = fmaf(cz, zq.x, fmaf(cy, xy.y, __fmul_rn(cx, xy.x)));
            const float d2  = __fsub_rn(__fadd_rn(cc, zq.y), __fmul_rn(2.0f, dot));
            const float    T  = __shfl(ld2, 31, 64);
            const unsigned Ti = __shfl(lidx, 31, 64);
            const bool qf = (d2 < T) || (d2 == T && (unsigned)p2 < Ti);
            unsigned long long mask = __ballot(qf);
            while (mask) {
                const int l = __ffsll(mask) - 1;
                const float    cd2  = __shfl(d2, l, 64);
                const unsigned cidx = (unsigned)(j0 + l);
                float    pv = __shfl_up(ld2, 1, 64);
                unsigned pi = __shfl_up(lidx, 1, 64);
                if (lane == 0) { pv = cd2; pi = cidx; }
                const bool mlt = (ld2 < cd2) || (ld2 == cd2 && lidx < cidx);
                const bool plt = (pv  < cd2) || (pv  == cd2 && pi   < cidx);
                ld2  = mlt ? ld2  : (plt ? cd2  : pv);
                lidx = mlt ? lidx : (plt ? cidx : pi);
                mask &= (mask - 1);
            }
        }
        if (lane < KNN) nbr[((size_t)b * P_OUT + p) * KNN + lane] = (int)lidx;
    }
}

// ---------------------------------------------------------------------------
// pconv: per center -- WeightNet (32x16) then inner einsum (128x16 over K=32),
// writes bf16 nf[bp][c*16+m]. XCD affinity: batch = blockIdx % 8.
// ---------------------------------------------------------------------------
__global__ __launch_bounds__(128) void pconv_kernel(const float* __restrict__ coords,
                                                    const float* __restrict__ feats,
                                                    const float* __restrict__ out_coords,
                                                    const int* __restrict__ nbr,
                                                    const float* __restrict__ wn_w,
                                                    const float* __restrict__ wn_b,
                                                    unsigned short* __restrict__ nf) {
    const int bp  = (blockIdx.x & 7) * P_OUT + (blockIdx.x >> 3);
    const int b   = bp >> 11;
    const int tid = threadIdx.x;
    __shared__ __align__(16) float wmat[32][16];
    __shared__ int nidx[32];
    __shared__ float ctr[3];
    if (tid < 32) nidx[tid] = nbr[(size_t)bp * KNN + tid];
    if (tid < 3)  ctr[tid]  = out_coords[(size_t)bp * 3 + tid];
    __syncthreads();
    {
        const int k  = tid >> 2;
        const int m0 = (tid & 3) * 4;
        const int n  = nidx[k];
        const float* pc = coords + ((size_t)b * NPTS + n) * 3;
        const float dx = pc[0] - ctr[0];
        const float dy = pc[1] - ctr[1];
        const float dz = pc[2] - ctr[2];
        #pragma unroll
        for (int mm = 0; mm < 4; ++mm) {
            const int m = m0 + mm;
            float a = dx * wn_w[m*3+0] + dy * wn_w[m*3+1] + dz * wn_w[m*3+2] + wn_b[m];
            wmat[k][m] = (a >= 0.0f) ? a : 0.2f * a;   // LeakyReLU(0.2)
        }
    }
    __syncthreads();
    const int c = tid;  // channel 0..127
    float acc[16];
    #pragma unroll
    for (int m = 0; m < 16; ++m) acc[m] = 0.0f;
    const float* fb = feats + (size_t)b * NPTS * CIN;
    #pragma unroll 4
    for (int k = 0; k < 32; ++k) {
        const float f = fb[(size_t)nidx[k] * CIN + c];
        const float4* wr = (const float4*)(&wmat[k][0]);
        const float4 w0 = wr[0], w1 = wr[1], w2 = wr[2], w3 = wr[3];
        acc[0]  += f * w0.x;  acc[1]  += f * w0.y;  acc[2]  += f * w0.z;  acc[3]  += f * w0.w;
        acc[4]  += f * w1.x;  acc[5]  += f * w1.y;  acc[6]  += f * w1.z;  acc[7]  += f * w1.w;
        acc[8]  += f * w2.x;  acc[9]  += f * w2.y;  acc[10] += f * w2.z;  acc[11] += f * w2.w;
        acc[12] += f * w3.x;  acc[13] += f * w3.y;  acc[14] += f * w3.z;  acc[15] += f * w3.w;
    }
    unsigned u[8];
    #pragma unroll
    for (int m = 0; m < 8; ++m) {
        const unsigned lo = f2bf(acc[2*m]);
        const unsigned hi = f2bf(acc[2*m+1]);
        u[m] = lo | (hi << 16);
    }
    uint4* dst = (uint4*)(nf + (size_t)bp * 2048 + c * 16);
    dst[0] = make_uint4(u[0], u[1], u[2], u[3]);
    dst[1] = make_uint4(u[4], u[5], u[6], u[7]);
}

// ---------------------------------------------------------------------------
// GEMM: C[16384,256] = A[16384,2048](bf16) * lin_w^T(bf16) + bias.
// 128x128 tile, BK=32, 4 waves each 64x64, mfma_f32_16x16x32_bf16.
// LDS rows padded to 40 elems (80B) -> 2-way (free) bank pattern.
// ---------------------------------------------------------------------------
__global__ __launch_bounds__(256) void gemm_kernel(const unsigned short* __restrict__ A,
                                                   const unsigned short* __restrict__ Bw,
                                                   const float* __restrict__ bias,
                                                   float* __restrict__ C) {
    __shared__ __align__(16) unsigned short Als[128 * 40];
    __shared__ __align__(16) unsigned short Bls[128 * 40];
    const int tid = threadIdx.x;
    const int m0  = blockIdx.x * 128;
    const int cb  = blockIdx.y;
    const int wv  = tid >> 6, lane = tid & 63;
    const int wr  = wv >> 1,  wc   = wv & 1;
    const int sr  = tid >> 1;
    const int ko  = (tid & 1) * 16;
    const int rr  = lane & 15, kg = lane >> 4;

    f32x4 acc[4][4] = {};

    for (int kt = 0; kt < 2048 / 32; ++kt) {
        const uint4* as = (const uint4*)(A  + (size_t)(m0 + sr) * 2048 + kt * 32 + ko);
        const uint4 a0 = as[0], a1 = as[1];
        const uint4* bs = (const uint4*)(Bw + (size_t)(cb * 128 + sr) * 2048 + kt * 32 + ko);
        const uint4 b0 = bs[0], b1 = bs[1];
        __syncthreads();
        *(uint4*)(&Als[sr * 40 + ko])     = a0;
        *(uint4*)(&Als[sr * 40 + ko + 8]) = a1;
        *(uint4*)(&Bls[sr * 40 + ko])     = b0;
        *(uint4*)(&Bls[sr * 40 + ko + 8]) = b1;
        __syncthreads();
        bf16x8 af[4], bfv[4];
        #pragma unroll
        for (int i = 0; i < 4; ++i)
            af[i] = *(const bf16x8*)(&Als[(wr*64 + i*16 + rr) * 40 + kg * 8]);
        #pragma unroll
        for (int j = 0; j < 4; ++j)
            bfv[j] = *(const bf16x8*)(&Bls[(wc*64 + j*16 + rr) * 40 + kg * 8]);
        #pragma unroll
        for (int i = 0; i < 4; ++i)
            #pragma unroll
            for (int j = 0; j < 4; ++j)
                acc[i][j] = __builtin_amdgcn_mfma_f32_16x16x32_bf16(af[i], bfv[j], acc[i][j], 0, 0, 0);
    }
    const int rg = lane >> 4;
    #pragma unroll
    for (int j = 0; j < 4; ++j) {
        const int col = cb * 128 + wc * 64 + j * 16 + rr;
        const float bv = bias[col];
        #pragma unroll
        for (int i = 0; i < 4; ++i) {
            const int row = m0 + wr * 64 + i * 16 + rg * 4;
            #pragma unroll
            for (int g = 0; g < 4; ++g)
                C[(size_t)(row + g) * 256 + col] = acc[i][j][g] + bv;
        }
    }
}

// ---------------------------------------------------------------------------
extern "C" void kernel_launch(void* const* d_in, const int* in_sizes, int n_in,
                              void* d_out, int out_size, void* d_ws, size_t ws_size,
                              hipStream_t stream) {
    const float* coords = (const float*)d_in[0];
    const float* feats  = (const float*)d_in[1];
    const float* wn_w   = (const float*)d_in[2];
    const float* wn_b   = (const float*)d_in[3];
    const float* lin_w  = (const float*)d_in[4];
    const float* lin_b  = (const float*)d_in[5];

    float* out        = (float*)d_out;
    float* out_coords = out;                       // (8,2048,3)
    float* out_nf     = out + NB * P_OUT * 3;      // (8,2048,256)

    char* ws = (char*)d_ws;
    int*            nbr  = (int*)ws;                                    // 2 MB
    float2*         zp   = (float2*)(ws + ((size_t)2  << 20));          // 0.5 MB
    unsigned short* lwbf = (unsigned short*)(ws + ((size_t)2560 << 10));// 1 MB
    unsigned short* nf   = (unsigned short*)(ws + ((size_t)4  << 20));  // 64 MB

    prep_kernel <<<2048, 256, 0, stream>>>(coords, lin_w, zp, lwbf);
    fps_kernel  <<<NB, 1024, 0, stream>>>(coords, out_coords);
    knn_kernel  <<<256, 1024, 0, stream>>>(coords, zp, out_coords, nbr);
    pconv_kernel<<<NB * P_OUT, 128, 0, stream>>>(coords, feats, out_coords, nbr, wn_w, wn_b, nf);
    gemm_kernel <<<dim3(128, 2), 256, 0, stream>>>(nf, lwbf, lin_b, out_nf);
}

// Round 5
// 3528.075 us; speedup vs baseline: 1.0328x; 1.0328x over previous
//
#include <hip/hip_runtime.h>
#include <hip/hip_bf16.h>

#define NB    8
#define NPTS  8192
#define P_OUT 2048
#define KNN   32
#define CIN   128
#define CMID  16
#define COUT  256

typedef __bf16 bf16x8 __attribute__((ext_vector_type(8)));
typedef float  f32x4  __attribute__((ext_vector_type(4)));
typedef float  f32x2  __attribute__((ext_vector_type(2)));

// Correctly-rounded f32 sqrt via double (53>=2p+2 bits: double-rounding safe).
__device__ __forceinline__ float sqrt_rn_f32(float x) { return (float)sqrt((double)x); }

// RNE float->bf16 (finite inputs only)
__device__ __forceinline__ unsigned short f2bf(float x) {
    unsigned u = __float_as_uint(x);
    return (unsigned short)((u + 0x7FFFu + ((u >> 16) & 1u)) >> 16);
}

// Full-wave (64-lane) max via DPP; result valid in lane 63.
// Sequence: xor1(quad_perm[1,0,3,2]), xor2(quad_perm[2,3,0,1]),
// row_half_mirror, row_mirror, row_bcast:15 (rows 1,3), row_bcast:31 (rows 2,3).
__device__ __forceinline__ float wave_max_dpp(float x) {
    int v, t;
    v = __float_as_int(x);
    t = __builtin_amdgcn_update_dpp(v, v, 0xB1, 0xF, 0xF, false);
    x = fmaxf(x, __int_as_float(t));
    v = __float_as_int(x);
    t = __builtin_amdgcn_update_dpp(v, v, 0x4E, 0xF, 0xF, false);
    x = fmaxf(x, __int_as_float(t));
    v = __float_as_int(x);
    t = __builtin_amdgcn_update_dpp(v, v, 0x141, 0xF, 0xF, false);
    x = fmaxf(x, __int_as_float(t));
    v = __float_as_int(x);
    t = __builtin_amdgcn_update_dpp(v, v, 0x140, 0xF, 0xF, false);
    x = fmaxf(x, __int_as_float(t));
    v = __float_as_int(x);
    t = __builtin_amdgcn_update_dpp(v, v, 0x142, 0xA, 0xF, false);
    x = fmaxf(x, __int_as_float(t));
    v = __float_as_int(x);
    t = __builtin_amdgcn_update_dpp(v, v, 0x143, 0xC, 0xF, false);
    x = fmaxf(x, __int_as_float(t));
    return x;
}

// ---------------------------------------------------------------------------
// prep: (z, |p|^2) per point (|p|^2 = no-FMA rn chain), and lin_w -> bf16
// ---------------------------------------------------------------------------
__global__ __launch_bounds__(256) void prep_kernel(const float* __restrict__ coords,
                                                   const float* __restrict__ lin_w,
                                                   float2* __restrict__ zp,
                                                   unsigned short* __restrict__ lwbf) {
    const int i = blockIdx.x * 256 + threadIdx.x;
    if (i < NB * NPTS) {
        const float* pc = coords + (size_t)i * 3;
        const float x = pc[0], y = pc[1], z = pc[2];
        float t = __fmul_rn(x, x);
        t = __fadd_rn(t, __fmul_rn(y, y));
        t = __fadd_rn(t, __fmul_rn(z, z));
        zp[i] = make_float2(z, t);
    }
    if (i < COUT * CIN * CMID) lwbf[i] = f2bf(lin_w[i]);
}

// ---------------------------------------------------------------------------
// FPS: one workgroup per batch, 512 thr x 16 consecutive points in registers
// (f32x2-packed -> v_pk_add/mul_f32). Semantics identical to the round-1
// PASSING version: no-FMA rn d^2 chain (contract off), f32 fmin chain,
// argmax-over-sqrt ties via correctly-rounded-sqrt ulp window, min-index
// tie-break via LDS atomicMin, 3-barrier winslot/owner-publish skeleton.
// ---------------------------------------------------------------------------
__global__ __launch_bounds__(512) void fps_kernel(const float* __restrict__ coords,
                                                  float* __restrict__ out_coords) {
    #pragma clang fp contract(off)
    const int b    = blockIdx.x;
    const int tid  = threadIdx.x;
    const int lane = tid & 63;
    const int wv   = tid >> 6;                    // 8 waves
    const float* cb = coords + (size_t)b * (NPTS * 3);
    float* outc = out_coords + (size_t)b * (P_OUT * 3);

    __shared__ __align__(16) float warr[8];
    __shared__ unsigned winslot;
    __shared__ float csl[3];

    f32x2 pxv[8], pyv[8], pzv[8], d2v[8];
    {
        float buf[48];
        const float4* g4 = (const float4*)cb;
        #pragma unroll
        for (int i = 0; i < 12; ++i) {
            float4 v = g4[tid * 12 + i];
            buf[i*4+0] = v.x; buf[i*4+1] = v.y; buf[i*4+2] = v.z; buf[i*4+3] = v.w;
        }
        #pragma unroll
        for (int i = 0; i < 8; ++i) {
            pxv[i] = f32x2{buf[(2*i)*3+0], buf[(2*i+1)*3+0]};
            pyv[i] = f32x2{buf[(2*i)*3+1], buf[(2*i+1)*3+1]};
            pzv[i] = f32x2{buf[(2*i)*3+2], buf[(2*i+1)*3+2]};
            d2v[i] = f32x2{__builtin_inff(), __builtin_inff()};
        }
    }
    if (tid == 0) {
        csl[0] = pxv[0][0]; csl[1] = pyv[0][0]; csl[2] = pzv[0][0];  // seed = point 0
        winslot = 0xFFFFFFFFu;
    }
    __syncthreads();
    float cx = csl[0], cy = csl[1], cz = csl[2];
    const unsigned base = (unsigned)tid * 16;

    for (int s = 0; s < P_OUT; ++s) {
        if (tid == 0) { outc[s*3+0] = cx; outc[s*3+1] = cy; outc[s*3+2] = cz; }
        if (s == P_OUT - 1) break;

        // min-update in d^2 (sub/mul/add rn chain, contraction off), track max
        const f32x2 cx2 = {cx, cx}, cy2 = {cy, cy}, cz2 = {cz, cz};
        f32x2 tmax2 = {0.0f, 0.0f};
        #pragma unroll
        for (int i = 0; i < 8; ++i) {
            const f32x2 dx = pxv[i] - cx2;
            const f32x2 dy = pyv[i] - cy2;
            const f32x2 dz = pzv[i] - cz2;
            f32x2 t = dx * dx;
            t = t + dy * dy;
            t = t + dz * dz;
            const f32x2 nd = __builtin_elementwise_min(d2v[i], t);
            d2v[i] = nd;
            tmax2 = __builtin_elementwise_max(tmax2, nd);
        }
        const float tmax = fmaxf(tmax2[0], tmax2[1]);

        // wave max via DPP (valid in lane 63)
        const float wmaxl = wave_max_dpp(tmax);
        if (lane == 63) warr[wv] = wmaxl;
        __syncthreads();  // BAR A

        const float4 q0 = *(const float4*)(warr + 0);
        const float4 q1 = *(const float4*)(warr + 4);
        const float gmax = fmaxf(fmaxf(fmaxf(q0.x, q0.y), fmaxf(q0.z, q0.w)),
                                 fmaxf(fmaxf(q1.x, q1.y), fmaxf(q1.z, q1.w)));
        const float wmax = (wv < 4) ? ((wv < 2) ? (wv ? q0.y : q0.x) : (wv == 2 ? q0.z : q0.w))
                                    : ((wv < 6) ? (wv == 4 ? q1.x : q1.y) : (wv == 6 ? q1.z : q1.w));

        // only waves within 3 ulps of gmax can hold the winner (window <= 4 ulps)
        if (__float_as_uint(wmax) + 3u >= __float_as_uint(gmax)) {
            const float s_ = sqrt_rn_f32(gmax);
            float t_lo = gmax;
            const unsigned gb = __float_as_uint(gmax);
            #pragma unroll
            for (int j = 1; j <= 3; ++j) {
                float v = __uint_as_float(gb - j);
                if (sqrt_rn_f32(v) == s_) t_lo = v;   // monotone: extends window downward
            }
            unsigned cand = 0xFFFFFFFFu;
            #pragma unroll
            for (int i = 7; i >= 0; --i) {            // descending: keep smallest idx
                if (d2v[i][1] >= t_lo) cand = base + 2*i + 1;
                if (d2v[i][0] >= t_lo) cand = base + 2*i;
            }
            if (cand != 0xFFFFFFFFu) atomicMin(&winslot, cand);  // smallest global idx
        }
        __syncthreads();  // BAR B

        const unsigned widx = winslot;
        if ((widx >> 4) == (unsigned)tid) {   // owner publishes centroid (static idx)
            #pragma unroll
            for (int i = 0; i < 8; ++i) {
                if (widx == base + 2*i)     { csl[0]=pxv[i][0]; csl[1]=pyv[i][0]; csl[2]=pzv[i][0]; }
                if (widx == base + 2*i + 1) { csl[0]=pxv[i][1]; csl[1]=pyv[i][1]; csl[2]=pzv[i][1]; }
            }
        }
        __syncthreads();  // BAR C
        if (tid == 0) winslot = 0xFFFFFFFFu;  // safe: next atomics after next BAR A
        cx = csl[0]; cy = csl[1]; cz = csl[2];
    }
}

// ---------------------------------------------------------------------------
// KNN: wave-per-center, distributed sorted top-32 list in lanes (lex (d2,idx)
// order == lax.top_k stability). d2 = f32 gram trick with the contraction's
// FMA chain: dot = fma(cz,z, fma(cy,y, cx*x)); cc/pp no-FMA rn chains.
// xy staged in 64KB LDS; (z,|p|^2) streamed from L2. PASSED round 4 verbatim.
// ---------------------------------------------------------------------------
__global__ __launch_bounds__(1024) void knn_kernel(const float* __restrict__ coords,
                                                   const float2* __restrict__ zp,
                                                   const float* __restrict__ out_coords,
                                                   int* __restrict__ nbr) {
    const int b     = blockIdx.x & 7;
    const int chunk = blockIdx.x >> 3;
    const int tid   = threadIdx.x;
    const int wv    = tid >> 6, lane = tid & 63;
    __shared__ float2 sxy[NPTS];  // 64 KB exactly
    {
        float buf[24];
        const float4* g4 = (const float4*)(coords + (size_t)b * (NPTS * 3));
        #pragma unroll
        for (int i = 0; i < 6; ++i) {
            float4 v = g4[tid * 6 + i];
            buf[i*4+0]=v.x; buf[i*4+1]=v.y; buf[i*4+2]=v.z; buf[i*4+3]=v.w;
        }
        #pragma unroll
        for (int i = 0; i < 8; ++i)
            sxy[tid*8 + i] = make_float2(buf[i*3+0], buf[i*3+1]);
    }
    __syncthreads();
    const float2* zpb = zp + (size_t)b * NPTS;

    for (int ci = 0; ci < 4; ++ci) {
        const int p = chunk * 64 + wv * 4 + ci;
        const float* oc = out_coords + ((size_t)b * P_OUT + p) * 3;
        const float cx = oc[0], cy = oc[1], cz = oc[2];
        const float cc = __fadd_rn(__fadd_rn(__fmul_rn(cx,cx), __fmul_rn(cy,cy)), __fmul_rn(cz,cz));
        float ld2 = __builtin_inff();
        unsigned lidx = 0x7FFFFFFFu;
        for (int j0 = 0; j0 < NPTS; j0 += 64) {
            const int p2 = j0 + lane;
            const float2 xy = sxy[p2];
            const float2 zq = zpb[p2];
            const float dot = fmaf(cz, zq.x, fmaf(cy, xy.y, __fmul_rn(cx, xy.x)));
            const float d2  = __fsub_rn(__fadd_rn(cc, zq.y), __fmul_rn(2.0f, dot));
            const float    T  = __shfl(ld2, 31, 64);
            const unsigned Ti = __shfl(lidx, 31, 64);
            const bool qf = (d2 < T) || (d2 == T && (unsigned)p2 < Ti);
            unsigned long long mask = __ballot(qf);
            while (mask) {
                const int l = __ffsll(mask) - 1;
                const float    cd2  = __shfl(d2, l, 64);
                const unsigned cidx = (unsigned)(j0 + l);
                float    pv = __shfl_up(ld2, 1, 64);
                unsigned pi = __shfl_up(lidx, 1, 64);
                if (lane == 0) { pv = cd2; pi = cidx; }
                const bool mlt = (ld2 < cd2) || (ld2 == cd2 && lidx < cidx);
                const bool plt = (pv  < cd2) || (pv  == cd2 && pi   < cidx);
                ld2  = mlt ? ld2  : (plt ? cd2  : pv);
                lidx = mlt ? lidx : (plt ? cidx : pi);
                mask &= (mask - 1);
            }
        }
        if (lane < KNN) nbr[((size_t)b * P_OUT + p) * KNN + lane] = (int)lidx;
    }
}

// ---------------------------------------------------------------------------
// pconv: per center -- WeightNet (32x16) then inner einsum (128x16 over K=32),
// writes bf16 nf[bp][c*16+m]. XCD affinity: batch = blockIdx % 8.
// ---------------------------------------------------------------------------
__global__ __launch_bounds__(128) void pconv_kernel(const float* __restrict__ coords,
                                                    const float* __restrict__ feats,
                                                    const float* __restrict__ out_coords,
                                                    const int* __restrict__ nbr,
                                                    const float* __restrict__ wn_w,
                                                    const float* __restrict__ wn_b,
                                                    unsigned short* __restrict__ nf) {
    const int bp  = (blockIdx.x & 7) * P_OUT + (blockIdx.x >> 3);
    const int b   = bp >> 11;
    const int tid = threadIdx.x;
    __shared__ __align__(16) float wmat[32][16];
    __shared__ int nidx[32];
    __shared__ float ctr[3];
    if (tid < 32) nidx[tid] = nbr[(size_t)bp * KNN + tid];
    if (tid < 3)  ctr[tid]  = out_coords[(size_t)bp * 3 + tid];
    __syncthreads();
    {
        const int k  = tid >> 2;
        const int m0 = (tid & 3) * 4;
        const int n  = nidx[k];
        const float* pc = coords + ((size_t)b * NPTS + n) * 3;
        const float dx = pc[0] - ctr[0];
        const float dy = pc[1] - ctr[1];
        const float dz = pc[2] - ctr[2];
        #pragma unroll
        for (int mm = 0; mm < 4; ++mm) {
            const int m = m0 + mm;
            float a = dx * wn_w[m*3+0] + dy * wn_w[m*3+1] + dz * wn_w[m*3+2] + wn_b[m];
            wmat[k][m] = (a >= 0.0f) ? a : 0.2f * a;   // LeakyReLU(0.2)
        }
    }
    __syncthreads();
    const int c = tid;  // channel 0..127
    float acc[16];
    #pragma unroll
    for (int m = 0; m < 16; ++m) acc[m] = 0.0f;
    const float* fb = feats + (size_t)b * NPTS * CIN;
    #pragma unroll 4
    for (int k = 0; k < 32; ++k) {
        const float f = fb[(size_t)nidx[k] * CIN + c];
        const float4* wr = (const float4*)(&wmat[k][0]);
        const float4 w0 = wr[0], w1 = wr[1], w2 = wr[2], w3 = wr[3];
        acc[0]  += f * w0.x;  acc[1]  += f * w0.y;  acc[2]  += f * w0.z;  acc[3]  += f * w0.w;
        acc[4]  += f * w1.x;  acc[5]  += f * w1.y;  acc[6]  += f * w1.z;  acc[7]  += f * w1.w;
        acc[8]  += f * w2.x;  acc[9]  += f * w2.y;  acc[10] += f * w2.z;  acc[11] += f * w2.w;
        acc[12] += f * w3.x;  acc[13] += f * w3.y;  acc[14] += f * w3.z;  acc[15] += f * w3.w;
    }
    unsigned u[8];
    #pragma unroll
    for (int m = 0; m < 8; ++m) {
        const unsigned lo = f2bf(acc[2*m]);
        const unsigned hi = f2bf(acc[2*m+1]);
        u[m] = lo | (hi << 16);
    }
    uint4* dst = (uint4*)(nf + (size_t)bp * 2048 + c * 16);
    dst[0] = make_uint4(u[0], u[1], u[2], u[3]);
    dst[1] = make_uint4(u[4], u[5], u[6], u[7]);
}

// ---------------------------------------------------------------------------
// GEMM: C[16384,256] = A[16384,2048](bf16) * lin_w^T(bf16) + bias.
// 128x128 tile, BK=32, 4 waves each 64x64, mfma_f32_16x16x32_bf16.
// ---------------------------------------------------------------------------
__global__ __launch_bounds__(256) void gemm_kernel(const unsigned short* __restrict__ A,
                                                   const unsigned short* __restrict__ Bw,
                                                   const float* __restrict__ bias,
                                                   float* __restrict__ C) {
    __shared__ __align__(16) unsigned short Als[128 * 40];
    __shared__ __align__(16) unsigned short Bls[128 * 40];
    const int tid = threadIdx.x;
    const int m0  = blockIdx.x * 128;
    const int cb  = blockIdx.y;
    const int wv  = tid >> 6, lane = tid & 63;
    const int wr  = wv >> 1,  wc   = wv & 1;
    const int sr  = tid >> 1;
    const int ko  = (tid & 1) * 16;
    const int rr  = lane & 15, kg = lane >> 4;

    f32x4 acc[4][4] = {};

    for (int kt = 0; kt < 2048 / 32; ++kt) {
        const uint4* as = (const uint4*)(A  + (size_t)(m0 + sr) * 2048 + kt * 32 + ko);
        const uint4 a0 = as[0], a1 = as[1];
        const uint4* bs = (const uint4*)(Bw + (size_t)(cb * 128 + sr) * 2048 + kt * 32 + ko);
        const uint4 b0 = bs[0], b1 = bs[1];
        __syncthreads();
        *(uint4*)(&Als[sr * 40 + ko])     = a0;
        *(uint4*)(&Als[sr * 40 + ko + 8]) = a1;
        *(uint4*)(&Bls[sr * 40 + ko])     = b0;
        *(uint4*)(&Bls[sr * 40 + ko + 8]) = b1;
        __syncthreads();
        bf16x8 af[4], bfv[4];
        #pragma unroll
        for (int i = 0; i < 4; ++i)
            af[i] = *(const bf16x8*)(&Als[(wr*64 + i*16 + rr) * 40 + kg * 8]);
        #pragma unroll
        for (int j = 0; j < 4; ++j)
            bfv[j] = *(const bf16x8*)(&Bls[(wc*64 + j*16 + rr) * 40 + kg * 8]);
        #pragma unroll
        for (int i = 0; i < 4; ++i)
            #pragma unroll
            for (int j = 0; j < 4; ++j)
                acc[i][j] = __builtin_amdgcn_mfma_f32_16x16x32_bf16(af[i], bfv[j], acc[i][j], 0, 0, 0);
    }
    const int rg = lane >> 4;
    #pragma unroll
    for (int j = 0; j < 4; ++j) {
        const int col = cb * 128 + wc * 64 + j * 16 + rr;
        const float bv = bias[col];
        #pragma unroll
        for (int i = 0; i < 4; ++i) {
            const int row = m0 + wr * 64 + i * 16 + rg * 4;
            #pragma unroll
            for (int g = 0; g < 4; ++g)
                C[(size_t)(row + g) * 256 + col] = acc[i][j][g] + bv;
        }
    }
}

// ---------------------------------------------------------------------------
extern "C" void kernel_launch(void* const* d_in, const int* in_sizes, int n_in,
                              void* d_out, int out_size, void* d_ws, size_t ws_size,
                              hipStream_t stream) {
    const float* coords = (const float*)d_in[0];
    const float* feats  = (const float*)d_in[1];
    const float* wn_w   = (const float*)d_in[2];
    const float* wn_b   = (const float*)d_in[3];
    const float* lin_w  = (const float*)d_in[4];
    const float* lin_b  = (const float*)d_in[5];

    float* out        = (float*)d_out;
    float* out_coords = out;                       // (8,2048,3)
    float* out_nf     = out + NB * P_OUT * 3;      // (8,2048,256)

    char* ws = (char*)d_ws;
    int*            nbr  = (int*)ws;                                    // 2 MB
    float2*         zp   = (float2*)(ws + ((size_t)2  << 20));          // 0.5 MB
    unsigned short* lwbf = (unsigned short*)(ws + ((size_t)2560 << 10));// 1 MB
    unsigned short* nf   = (unsigned short*)(ws + ((size_t)4  << 20));  // 64 MB

    prep_kernel <<<2048, 256, 0, stream>>>(coords, lin_w, zp, lwbf);
    fps_kernel  <<<NB, 512, 0, stream>>>(coords, out_coords);
    knn_kernel  <<<256, 1024, 0, stream>>>(coords, zp, out_coords, nbr);
    pconv_kernel<<<NB * P_OUT, 128, 0, stream>>>(coords, feats, out_coords, nbr, wn_w, wn_b, nf);
    gemm_kernel <<<dim3(128, 2), 256, 0, stream>>>(nf, lwbf, lin_b, out_nf);
}

// Round 6
// 3047.919 us; speedup vs baseline: 1.1956x; 1.1575x over previous
//
#include <hip/hip_runtime.h>
#include <hip/hip_bf16.h>

#define NB    8
#define NPTS  8192
#define P_OUT 2048
#define KNN   32
#define CIN   128
#define CMID  16
#define COUT  256

typedef __bf16 bf16x8 __attribute__((ext_vector_type(8)));
typedef float  f32x4  __attribute__((ext_vector_type(4)));
typedef float  f32x2  __attribute__((ext_vector_type(2)));

// Correctly-rounded f32 sqrt via double (53>=2p+2 bits: double-rounding safe).
__device__ __forceinline__ float sqrt_rn_f32(float x) { return (float)sqrt((double)x); }

// RNE float->bf16 (finite inputs only)
__device__ __forceinline__ unsigned short f2bf(float x) {
    unsigned u = __float_as_uint(x);
    return (unsigned short)((u + 0x7FFFu + ((u >> 16) & 1u)) >> 16);
}

// Full-wave (64-lane) max via DPP; result valid in lane 63.
__device__ __forceinline__ float wave_max_dpp(float x) {
    int v, t;
    v = __float_as_int(x);
    t = __builtin_amdgcn_update_dpp(v, v, 0xB1, 0xF, 0xF, false);
    x = fmaxf(x, __int_as_float(t));
    v = __float_as_int(x);
    t = __builtin_amdgcn_update_dpp(v, v, 0x4E, 0xF, 0xF, false);
    x = fmaxf(x, __int_as_float(t));
    v = __float_as_int(x);
    t = __builtin_amdgcn_update_dpp(v, v, 0x141, 0xF, 0xF, false);
    x = fmaxf(x, __int_as_float(t));
    v = __float_as_int(x);
    t = __builtin_amdgcn_update_dpp(v, v, 0x140, 0xF, 0xF, false);
    x = fmaxf(x, __int_as_float(t));
    v = __float_as_int(x);
    t = __builtin_amdgcn_update_dpp(v, v, 0x142, 0xA, 0xF, false);
    x = fmaxf(x, __int_as_float(t));
    v = __float_as_int(x);
    t = __builtin_amdgcn_update_dpp(v, v, 0x143, 0xC, 0xF, false);
    x = fmaxf(x, __int_as_float(t));
    return x;
}

// ---------------------------------------------------------------------------
// prep: (z, |p|^2) per point (|p|^2 = no-FMA rn chain), and lin_w -> bf16
// ---------------------------------------------------------------------------
__global__ __launch_bounds__(256) void prep_kernel(const float* __restrict__ coords,
                                                   const float* __restrict__ lin_w,
                                                   float2* __restrict__ zp,
                                                   unsigned short* __restrict__ lwbf) {
    const int i = blockIdx.x * 256 + threadIdx.x;
    if (i < NB * NPTS) {
        const float* pc = coords + (size_t)i * 3;
        const float x = pc[0], y = pc[1], z = pc[2];
        float t = __fmul_rn(x, x);
        t = __fadd_rn(t, __fmul_rn(y, y));
        t = __fadd_rn(t, __fmul_rn(z, z));
        zp[i] = make_float2(z, t);
    }
    if (i < COUT * CIN * CMID) lwbf[i] = f2bf(lin_w[i]);
}

// ---------------------------------------------------------------------------
// FPS: one workgroup per batch, 512 thr x 16 consecutive points in registers
// (f32x2-packed). Selection semantics byte-identical to the PASSING round-5
// kernel (no-FMA rn d^2 chain, sqrt-ulp tie window, atomicMin min-index).
// Sync structure cut to 2 barriers/step:
//   - BAR C removed: centroid re-read from global coords[widx] (uniform addr,
//     L1/L2 broadcast) instead of owner-publish via LDS.
//   - winslot ping-pong (slot s&1), other slot reset right after BAR A.
//   - sqrt window computed speculatively from wave-max BEFORE BAR A (exact
//     for the gmax-holding wave; recomputed in the rare near-tie case).
// ---------------------------------------------------------------------------
__global__ __launch_bounds__(512) void fps_kernel(const float* __restrict__ coords,
                                                  float* __restrict__ out_coords) {
    #pragma clang fp contract(off)
    const int b    = blockIdx.x;
    const int tid  = threadIdx.x;
    const int lane = tid & 63;
    const int wv   = tid >> 6;                    // 8 waves
    const float* cb = coords + (size_t)b * (NPTS * 3);
    float* outc = out_coords + (size_t)b * (P_OUT * 3);

    __shared__ __align__(16) float warr[8];
    __shared__ unsigned winslot[2];

    f32x2 pxv[8], pyv[8], pzv[8], d2v[8];
    {
        float buf[48];
        const float4* g4 = (const float4*)cb;
        #pragma unroll
        for (int i = 0; i < 12; ++i) {
            float4 v = g4[tid * 12 + i];
            buf[i*4+0] = v.x; buf[i*4+1] = v.y; buf[i*4+2] = v.z; buf[i*4+3] = v.w;
        }
        #pragma unroll
        for (int i = 0; i < 8; ++i) {
            pxv[i] = f32x2{buf[(2*i)*3+0], buf[(2*i+1)*3+0]};
            pyv[i] = f32x2{buf[(2*i)*3+1], buf[(2*i+1)*3+1]};
            pzv[i] = f32x2{buf[(2*i)*3+2], buf[(2*i+1)*3+2]};
            d2v[i] = f32x2{__builtin_inff(), __builtin_inff()};
        }
    }
    if (tid == 0) { winslot[0] = 0xFFFFFFFFu; winslot[1] = 0xFFFFFFFFu; }
    // seed = point 0 (uniform global read, broadcast line)
    float cx = cb[0], cy = cb[1], cz = cb[2];
    __syncthreads();
    const unsigned base = (unsigned)tid * 16;

    for (int s = 0; s < P_OUT; ++s) {
        if (tid == 0) { outc[s*3+0] = cx; outc[s*3+1] = cy; outc[s*3+2] = cz; }
        if (s == P_OUT - 1) break;

        // min-update in d^2 (sub/mul/add rn chain, contraction off), track max
        const f32x2 cx2 = {cx, cx}, cy2 = {cy, cy}, cz2 = {cz, cz};
        f32x2 tmax2 = {0.0f, 0.0f};
        #pragma unroll
        for (int i = 0; i < 8; ++i) {
            const f32x2 dx = pxv[i] - cx2;
            const f32x2 dy = pyv[i] - cy2;
            const f32x2 dz = pzv[i] - cz2;
            f32x2 t = dx * dx;
            t = t + dy * dy;
            t = t + dz * dz;
            const f32x2 nd = __builtin_elementwise_min(d2v[i], t);
            d2v[i] = nd;
            tmax2 = __builtin_elementwise_max(tmax2, nd);
        }
        const float tmax = fmaxf(tmax2[0], tmax2[1]);

        // wave max via DPP; publish + broadcast to all lanes pre-barrier
        const float wmaxl = wave_max_dpp(tmax);
        if (lane == 63) warr[wv] = wmaxl;
        const float wmax = __shfl(wmaxl, 63, 64);

        // speculative sqrt-ulp window from wmax (hidden under BAR A wait);
        // exact when this wave holds gmax (wmax == gmax)
        const unsigned wb = __float_as_uint(wmax);
        const float s_sp = sqrt_rn_f32(wmax);
        float t_lo_sp = wmax;
        #pragma unroll
        for (int j = 1; j <= 3; ++j) {
            const float v = __uint_as_float(wb - j);
            if (sqrt_rn_f32(v) == s_sp) t_lo_sp = v;
        }
        __syncthreads();  // BAR A
        if (tid == 0) winslot[(s + 1) & 1] = 0xFFFFFFFFu;  // reset other slot

        const float4 q0 = *(const float4*)(warr + 0);
        const float4 q1 = *(const float4*)(warr + 4);
        const float gmax = fmaxf(fmaxf(fmaxf(q0.x, q0.y), fmaxf(q0.z, q0.w)),
                                 fmaxf(fmaxf(q1.x, q1.y), fmaxf(q1.z, q1.w)));

        // only waves within 3 ulps of gmax can hold the winner (window <= 4 ulps)
        if (wb + 3u >= __float_as_uint(gmax)) {
            float t_lo;
            if (wmax == gmax) {
                t_lo = t_lo_sp;                    // speculation exact
            } else {                               // rare near-tie: recompute
                const float s_ = sqrt_rn_f32(gmax);
                const unsigned gb = __float_as_uint(gmax);
                t_lo = gmax;
                #pragma unroll
                for (int j = 1; j <= 3; ++j) {
                    const float v = __uint_as_float(gb - j);
                    if (sqrt_rn_f32(v) == s_) t_lo = v;
                }
            }
            unsigned cand = 0xFFFFFFFFu;
            #pragma unroll
            for (int i = 7; i >= 0; --i) {         // descending: keep smallest idx
                if (d2v[i][1] >= t_lo) cand = base + 2*i + 1;
                if (d2v[i][0] >= t_lo) cand = base + 2*i;
            }
            if (cand != 0xFFFFFFFFu) atomicMin(&winslot[s & 1], cand);
        }
        __syncthreads();  // BAR B

        const unsigned widx = winslot[s & 1];
        // centroid from global (block-uniform address -> broadcast line)
        cx = cb[widx * 3 + 0];
        cy = cb[widx * 3 + 1];
        cz = cb[widx * 3 + 2];
    }
}

// ---------------------------------------------------------------------------
// KNN: wave-per-center, distributed sorted top-32 list in lanes (lex (d2,idx)
// order == lax.top_k stability). d2 = f32 gram trick with the contraction's
// FMA chain: dot = fma(cz,z, fma(cy,y, cx*x)); cc/pp no-FMA rn chains.
// xy staged in 64KB LDS; (z,|p|^2) streamed from L2. PASSED rounds 4-5.
// ---------------------------------------------------------------------------
__global__ __launch_bounds__(1024) void knn_kernel(const float* __restrict__ coords,
                                                   const float2* __restrict__ zp,
                                                   const float* __restrict__ out_coords,
                                                   int* __restrict__ nbr) {
    const int b     = blockIdx.x & 7;
    const int chunk = blockIdx.x >> 3;
    const int tid   = threadIdx.x;
    const int wv    = tid >> 6, lane = tid & 63;
    __shared__ float2 sxy[NPTS];  // 64 KB exactly
    {
        float buf[24];
        const float4* g4 = (const float4*)(coords + (size_t)b * (NPTS * 3));
        #pragma unroll
        for (int i = 0; i < 6; ++i) {
            float4 v = g4[tid * 6 + i];
            buf[i*4+0]=v.x; buf[i*4+1]=v.y; buf[i*4+2]=v.z; buf[i*4+3]=v.w;
        }
        #pragma unroll
        for (int i = 0; i < 8; ++i)
            sxy[tid*8 + i] = make_float2(buf[i*3+0], buf[i*3+1]);
    }
    __syncthreads();
    const float2* zpb = zp + (size_t)b * NPTS;

    for (int ci = 0; ci < 4; ++ci) {
        const int p = chunk * 64 + wv * 4 + ci;
        const float* oc = out_coords + ((size_t)b * P_OUT + p) * 3;
        const float cx = oc[0], cy = oc[1], cz = oc[2];
        const float cc = __fadd_rn(__fadd_rn(__fmul_rn(cx,cx), __fmul_rn(cy,cy)), __fmul_rn(cz,cz));
        float ld2 = __builtin_inff();
        unsigned lidx = 0x7FFFFFFFu;
        for (int j0 = 0; j0 < NPTS; j0 += 64) {
            const int p2 = j0 + lane;
            const float2 xy = sxy[p2];
            const float2 zq = zpb[p2];
            const float dot = fmaf(cz, zq.x, fmaf(cy, xy.y, __fmul_rn(cx, xy.x)));
            const float d2  = __fsub_rn(__fadd_rn(cc, zq.y), __fmul_rn(2.0f, dot));
            const float    T  = __shfl(ld2, 31, 64);
            const unsigned Ti = __shfl(lidx, 31, 64);
            const bool qf = (d2 < T) || (d2 == T && (unsigned)p2 < Ti);
            unsigned long long mask = __ballot(qf);
            while (mask) {
                const int l = __ffsll(mask) - 1;
                const float    cd2  = __shfl(d2, l, 64);
                const unsigned cidx = (unsigned)(j0 + l);
                float    pv = __shfl_up(ld2, 1, 64);
                unsigned pi = __shfl_up(lidx, 1, 64);
                if (lane == 0) { pv = cd2; pi = cidx; }
                const bool mlt = (ld2 < cd2) || (ld2 == cd2 && lidx < cidx);
                const bool plt = (pv  < cd2) || (pv  == cd2 && pi   < cidx);
                ld2  = mlt ? ld2  : (plt ? cd2  : pv);
                lidx = mlt ? lidx : (plt ? cidx : pi);
                mask &= (mask - 1);
            }
        }
        if (lane < KNN) nbr[((size_t)b * P_OUT + p) * KNN + lane] = (int)lidx;
    }
}

// ---------------------------------------------------------------------------
// pconv: per center -- WeightNet (32x16) then inner einsum (128x16 over K=32),
// writes bf16 nf[bp][c*16+m]. XCD affinity: batch = blockIdx % 8.
// ---------------------------------------------------------------------------
__global__ __launch_bounds__(128) void pconv_kernel(const float* __restrict__ coords,
                                                    const float* __restrict__ feats,
                                                    const float* __restrict__ out_coords,
                                                    const int* __restrict__ nbr,
                                                    const float* __restrict__ wn_w,
                                                    const float* __restrict__ wn_b,
                                                    unsigned short* __restrict__ nf) {
    const int bp  = (blockIdx.x & 7) * P_OUT + (blockIdx.x >> 3);
    const int b   = bp >> 11;
    const int tid = threadIdx.x;
    __shared__ __align__(16) float wmat[32][16];
    __shared__ int nidx[32];
    __shared__ float ctr[3];
    if (tid < 32) nidx[tid] = nbr[(size_t)bp * KNN + tid];
    if (tid < 3)  ctr[tid]  = out_coords[(size_t)bp * 3 + tid];
    __syncthreads();
    {
        const int k  = tid >> 2;
        const int m0 = (tid & 3) * 4;
        const int n  = nidx[k];
        const float* pc = coords + ((size_t)b * NPTS + n) * 3;
        const float dx = pc[0] - ctr[0];
        const float dy = pc[1] - ctr[1];
        const float dz = pc[2] - ctr[2];
        #pragma unroll
        for (int mm = 0; mm < 4; ++mm) {
            const int m = m0 + mm;
            float a = dx * wn_w[m*3+0] + dy * wn_w[m*3+1] + dz * wn_w[m*3+2] + wn_b[m];
            wmat[k][m] = (a >= 0.0f) ? a : 0.2f * a;   // LeakyReLU(0.2)
        }
    }
    __syncthreads();
    const int c = tid;  // channel 0..127
    float acc[16];
    #pragma unroll
    for (int m = 0; m < 16; ++m) acc[m] = 0.0f;
    const float* fb = feats + (size_t)b * NPTS * CIN;
    #pragma unroll 4
    for (int k = 0; k < 32; ++k) {
        const float f = fb[(size_t)nidx[k] * CIN + c];
        const float4* wr = (const float4*)(&wmat[k][0]);
        const float4 w0 = wr[0], w1 = wr[1], w2 = wr[2], w3 = wr[3];
        acc[0]  += f * w0.x;  acc[1]  += f * w0.y;  acc[2]  += f * w0.z;  acc[3]  += f * w0.w;
        acc[4]  += f * w1.x;  acc[5]  += f * w1.y;  acc[6]  += f * w1.z;  acc[7]  += f * w1.w;
        acc[8]  += f * w2.x;  acc[9]  += f * w2.y;  acc[10] += f * w2.z;  acc[11] += f * w2.w;
        acc[12] += f * w3.x;  acc[13] += f * w3.y;  acc[14] += f * w3.z;  acc[15] += f * w3.w;
    }
    unsigned u[8];
    #pragma unroll
    for (int m = 0; m < 8; ++m) {
        const unsigned lo = f2bf(acc[2*m]);
        const unsigned hi = f2bf(acc[2*m+1]);
        u[m] = lo | (hi << 16);
    }
    uint4* dst = (uint4*)(nf + (size_t)bp * 2048 + c * 16);
    dst[0] = make_uint4(u[0], u[1], u[2], u[3]);
    dst[1] = make_uint4(u[4], u[5], u[6], u[7]);
}

// ---------------------------------------------------------------------------
// GEMM: C[16384,256] = A[16384,2048](bf16) * lin_w^T(bf16) + bias.
// 128x128 tile, BK=32, 4 waves each 64x64, mfma_f32_16x16x32_bf16.
// ---------------------------------------------------------------------------
__global__ __launch_bounds__(256) void gemm_kernel(const unsigned short* __restrict__ A,
                                                   const unsigned short* __restrict__ Bw,
                                                   const float* __restrict__ bias,
                                                   float* __restrict__ C) {
    __shared__ __align__(16) unsigned short Als[128 * 40];
    __shared__ __align__(16) unsigned short Bls[128 * 40];
    const int tid = threadIdx.x;
    const int m0  = blockIdx.x * 128;
    const int cb  = blockIdx.y;
    const int wv  = tid >> 6, lane = tid & 63;
    const int wr  = wv >> 1,  wc   = wv & 1;
    const int sr  = tid >> 1;
    const int ko  = (tid & 1) * 16;
    const int rr  = lane & 15, kg = lane >> 4;

    f32x4 acc[4][4] = {};

    for (int kt = 0; kt < 2048 / 32; ++kt) {
        const uint4* as = (const uint4*)(A  + (size_t)(m0 + sr) * 2048 + kt * 32 + ko);
        const uint4 a0 = as[0], a1 = as[1];
        const uint4* bs = (const uint4*)(Bw + (size_t)(cb * 128 + sr) * 2048 + kt * 32 + ko);
        const uint4 b0 = bs[0], b1 = bs[1];
        __syncthreads();
        *(uint4*)(&Als[sr * 40 + ko])     = a0;
        *(uint4*)(&Als[sr * 40 + ko + 8]) = a1;
        *(uint4*)(&Bls[sr * 40 + ko])     = b0;
        *(uint4*)(&Bls[sr * 40 + ko + 8]) = b1;
        __syncthreads();
        bf16x8 af[4], bfv[4];
        #pragma unroll
        for (int i = 0; i < 4; ++i)
            af[i] = *(const bf16x8*)(&Als[(wr*64 + i*16 + rr) * 40 + kg * 8]);
        #pragma unroll
        for (int j = 0; j < 4; ++j)
            bfv[j] = *(const bf16x8*)(&Bls[(wc*64 + j*16 + rr) * 40 + kg * 8]);
        #pragma unroll
        for (int i = 0; i < 4; ++i)
            #pragma unroll
            for (int j = 0; j < 4; ++j)
                acc[i][j] = __builtin_amdgcn_mfma_f32_16x16x32_bf16(af[i], bfv[j], acc[i][j], 0, 0, 0);
    }
    const int rg = lane >> 4;
    #pragma unroll
    for (int j = 0; j < 4; ++j) {
        const int col = cb * 128 + wc * 64 + j * 16 + rr;
        const float bv = bias[col];
        #pragma unroll
        for (int i = 0; i < 4; ++i) {
            const int row = m0 + wr * 64 + i * 16 + rg * 4;
            #pragma unroll
            for (int g = 0; g < 4; ++g)
                C[(size_t)(row + g) * 256 + col] = acc[i][j][g] + bv;
        }
    }
}

// ---------------------------------------------------------------------------
extern "C" void kernel_launch(void* const* d_in, const int* in_sizes, int n_in,
                              void* d_out, int out_size, void* d_ws, size_t ws_size,
                              hipStream_t stream) {
    const float* coords = (const float*)d_in[0];
    const float* feats  = (const float*)d_in[1];
    const float* wn_w   = (const float*)d_in[2];
    const float* wn_b   = (const float*)d_in[3];
    const float* lin_w  = (const float*)d_in[4];
    const float* lin_b  = (const float*)d_in[5];

    float* out        = (float*)d_out;
    float* out_coords = out;                       // (8,2048,3)
    float* out_nf     = out + NB * P_OUT * 3;      // (8,2048,256)

    char* ws = (char*)d_ws;
    int*            nbr  = (int*)ws;                                    // 2 MB
    float2*         zp   = (float2*)(ws + ((size_t)2  << 20));          // 0.5 MB
    unsigned short* lwbf = (unsigned short*)(ws + ((size_t)2560 << 10));// 1 MB
    unsigned short* nf   = (unsigned short*)(ws + ((size_t)4  << 20));  // 64 MB

    prep_kernel <<<2048, 256, 0, stream>>>(coords, lin_w, zp, lwbf);
    fps_kernel  <<<NB, 512, 0, stream>>>(coords, out_coords);
    knn_kernel  <<<256, 1024, 0, stream>>>(coords, zp, out_coords, nbr);
    pconv_kernel<<<NB * P_OUT, 128, 0, stream>>>(coords, feats, out_coords, nbr, wn_w, wn_b, nf);
    gemm_kernel <<<dim3(128, 2), 256, 0, stream>>>(nf, lwbf, lin_b, out_nf);
}